// Round 9
// baseline (1002.225 us; speedup 1.0000x reference)
//
#include <hip/hip_runtime.h>
#include <math.h>

typedef unsigned short u16;
typedef _Float16 f16;
typedef __attribute__((ext_vector_type(8))) short bf16x8;
typedef __attribute__((ext_vector_type(8))) unsigned short u16x8;
typedef __attribute__((ext_vector_type(4))) float f32x4;
typedef __attribute__((ext_vector_type(4))) f16 f16x4;

#define D_MODEL 1024
#define SEQ_N   2048
#define HEADS   16
#define DHEAD   64
#define M3      3072
#define JSPLIT  2
#define JCHUNK  (SEQ_N / JSPLIT)   // 1024
#define NBLK    1024

#define GLOBAL_AS __attribute__((address_space(1)))
#define LDS_AS    __attribute__((address_space(3)))
#define ASYNC16(gp, lp) __builtin_amdgcn_global_load_lds( \
    (const GLOBAL_AS unsigned int*)(gp), (LDS_AS unsigned int*)(lp), 16, 0, 0)

__device__ __forceinline__ u16 f2bf(float f) {
  union { float f; unsigned int u; } v; v.f = f;
  unsigned int r = v.u + 0x7fffu + ((v.u >> 16) & 1u);  // RNE
  return (u16)(r >> 16);
}

// grid barrier: all NBLK blocks co-resident (4/CU by construction).
__device__ __forceinline__ void gridbar(unsigned* ctr) {
  __threadfence();           // release: flush L2 writes device-wide
  __syncthreads();
  if (threadIdx.x == 0) {
    __hip_atomic_fetch_add(ctr, 1u, __ATOMIC_ACQ_REL, __HIP_MEMORY_SCOPE_AGENT);
    unsigned v; long n = 0;
    do {
      __builtin_amdgcn_s_sleep(8);
      v = __hip_atomic_load(ctr, __ATOMIC_ACQUIRE, __HIP_MEMORY_SCOPE_AGENT);
    } while (v < NBLK && ++n < (1 << 21));   // bounded spin (safety valve)
  }
  __syncthreads();
}

union SM {
  struct { double ls[256], lss[256]; } red;          // 4 KB
  float tile[32][65];                                // 8.3 KB
  struct { u16 A[128 * 32]; u16 B[64 * 32]; } g;     // 12 KB GEMM staging
  u16 qk[64][130];                                   // 16.6 KB
  u16 v[128][66];                                    // 16.9 KB
  struct { u16 K[64][72]; f16 V[64][72]; } at;       // 18.4 KB
};

__global__ __launch_bounds__(256, 4) void mega(
    const float* __restrict__ x, const float* __restrict__ WQ,
    const float* __restrict__ WK, const float* __restrict__ WV,
    const float* __restrict__ W0, float* __restrict__ out,
    unsigned* ctr, double* part, u16* xnt, u16* Wp, u16* W0p,
    u16* Qt, u16* Kt, f16* Vb, u16* attnt, f16* Opart, float* Lpart) {
  __shared__ SM sm;
  __shared__ float sstat[2];
  int b = blockIdx.x, t = threadIdx.x;
  int lane = t & 63, w = t >> 6, g = lane >> 4, l16 = lane & 15;

  // ================= P0: LN partials + weight packing =================
  {
    const float4* x4 = (const float4*)x;
    double s = 0.0, ss = 0.0;
#pragma unroll
    for (int r = 0; r < 2; ++r) {
      float4 v = x4[b * 256 + t + r * 262144];
      s  += (double)v.x + (double)v.y + (double)v.z + (double)v.w;
      ss += (double)v.x * v.x + (double)v.y * v.y + (double)v.z * v.z + (double)v.w * v.w;
    }
    sm.red.ls[t] = s; sm.red.lss[t] = ss;
    __syncthreads();
    for (int off = 128; off > 0; off >>= 1) {
      if (t < off) { sm.red.ls[t] += sm.red.ls[t + off]; sm.red.lss[t] += sm.red.lss[t + off]; }
      __syncthreads();
    }
    if (t == 0) { part[2 * b] = sm.red.ls[0]; part[2 * b + 1] = sm.red.lss[0]; }
    __syncthreads();
    for (int u = b; u < 2560; u += NBLK) {
      if (u < 1536) {           // pack WQ/WK/WV 32c x 64dh tiles
        int z = u >> 9, rem = u & 511;
        int h = rem >> 5, cb = (rem & 31) * 32;
        const float* W = (z == 0) ? WQ : ((z == 1) ? WK : WV);
        int dh = t & 63, cl = t >> 6;
        for (int r = 0; r < 8; ++r) {
          int c = cl + r * 4;
          sm.tile[c][dh] = W[((size_t)h * D_MODEL + cb + c) * DHEAD + dh];
        }
        __syncthreads();
        int c2 = t & 31, d2 = t >> 5;
        for (int r = 0; r < 8; ++r) {
          int dd = d2 + r * 8;
          Wp[(size_t)((z * HEADS + h) * DHEAD + dd) * D_MODEL + cb + c2] =
              f2bf(sm.tile[c2][dd]);
        }
        __syncthreads();
      } else {                  // pack W0
        int idx = (u - 1536) * 256 + t;
        float4 v = ((const float4*)W0)[idx];
        unsigned int lo = (unsigned int)f2bf(v.x) | ((unsigned int)f2bf(v.y) << 16);
        unsigned int hi = (unsigned int)f2bf(v.z) | ((unsigned int)f2bf(v.w) << 16);
        uint2 o; o.x = lo; o.y = hi;
        *(uint2*)(&W0p[(size_t)idx * 4]) = o;
      }
    }
  }
  gridbar(ctr + 0);
  // ================= P1: final stats + normalize+transpose =================
  {
    double s = 0.0, ss = 0.0;
    for (int i = t; i < 1024; i += 256) { s += part[2 * i]; ss += part[2 * i + 1]; }
    sm.red.ls[t] = s; sm.red.lss[t] = ss;
    __syncthreads();
    for (int off = 128; off > 0; off >>= 1) {
      if (t < off) { sm.red.ls[t] += sm.red.ls[t + off]; sm.red.lss[t] += sm.red.lss[t + off]; }
      __syncthreads();
    }
    if (t == 0) {
      double inv = 1.0 / ((double)D_MODEL * (double)SEQ_N);
      double mean = sm.red.ls[0] * inv;
      double var  = sm.red.lss[0] * inv - mean * mean;
      sstat[0] = (float)mean;
      sstat[1] = (float)(1.0 / sqrt(var + 1e-5));
    }
    __syncthreads();
    float mean = sstat[0], rstd = sstat[1];
    int ib = (b & 31) * 64, cb = (b >> 5) * 32;   // 1024 units: 64i x 32c
#pragma unroll
    for (int r = 0; r < 2; ++r) {
      int c = (t >> 4) + r * 16;
      int i4 = (t & 15) * 4;
      float4 v = *(const float4*)(&x[(size_t)(cb + c) * SEQ_N + ib + i4]);
      sm.tile[c][i4 + 0] = (v.x - mean) * rstd;
      sm.tile[c][i4 + 1] = (v.y - mean) * rstd;
      sm.tile[c][i4 + 2] = (v.z - mean) * rstd;
      sm.tile[c][i4 + 3] = (v.w - mean) * rstd;
    }
    __syncthreads();
    {
      int i = t >> 2, c8 = (t & 3) * 8;
      u16x8 o;
#pragma unroll
      for (int j = 0; j < 8; ++j) o[j] = f2bf(sm.tile[c8 + j][i]);
      *(u16x8*)(&xnt[(size_t)(ib + i) * D_MODEL + cb + c8]) = o;
    }
  }
  gridbar(ctr + 16);
  // ================= P2: QKV GEMM 128x64 (768 blocks) =================
  if (b < 768) {
    int xcd = b & 7, s2 = b >> 3;
    int mt = xcd * 3 + (s2 % 3);
    int nt = s2 / 3;
    int mb = mt * 128, nb = nt * 64;
    f32x4 acc[2][4];
#pragma unroll
    for (int i = 0; i < 2; ++i)
#pragma unroll
      for (int j = 0; j < 4; ++j) acc[i][j] = (f32x4){0.f, 0.f, 0.f, 0.f};
    int srow = t >> 2, scol = (t & 3) * 8;
    const u16* Ag0 = Wp + (size_t)(mb + srow) * D_MODEL + scol;
    const u16* Ag1 = Wp + (size_t)(mb + 64 + srow) * D_MODEL + scol;
    const u16* Bg  = xnt + (size_t)(nb + srow) * D_MODEL + scol;
    for (int kb = 0; kb < D_MODEL; kb += 32) {
      ASYNC16(Ag0 + kb, &sm.g.A[t * 8]);
      ASYNC16(Ag1 + kb, &sm.g.A[2048 + t * 8]);
      ASYNC16(Bg + kb, &sm.g.B[t * 8]);
      __syncthreads();
      bf16x8 af[2], bf[4];
#pragma unroll
      for (int tm = 0; tm < 2; ++tm)
        af[tm] = *(const bf16x8*)(&sm.g.A[(w * 32 + tm * 16 + l16) * 32 + g * 8]);
#pragma unroll
      for (int tn = 0; tn < 4; ++tn)
        bf[tn] = *(const bf16x8*)(&sm.g.B[(tn * 16 + l16) * 32 + g * 8]);
#pragma unroll
      for (int tm = 0; tm < 2; ++tm)
#pragma unroll
        for (int tn = 0; tn < 4; ++tn)
          acc[tm][tn] = __builtin_amdgcn_mfma_f32_16x16x32_bf16(af[tm], bf[tn],
                                                                acc[tm][tn], 0, 0, 0);
      __syncthreads();
    }
    if (mb < 2 * D_MODEL) {
#pragma unroll
      for (int tm = 0; tm < 2; ++tm) {
        int m0 = w * 32 + tm * 16 + g * 4;
#pragma unroll
        for (int tn = 0; tn < 4; ++tn) {
          int nl = tn * 16 + l16;
          ushort4 o;
          o.x = f2bf(acc[tm][tn][0]); o.y = f2bf(acc[tm][tn][1]);
          o.z = f2bf(acc[tm][tn][2]); o.w = f2bf(acc[tm][tn][3]);
          *(ushort4*)(&sm.qk[nl][m0]) = o;
        }
      }
      __syncthreads();
      u16* T = (mb < D_MODEL) ? Qt : Kt;
      int mbase = (mb < D_MODEL) ? mb : mb - D_MODEL;
#pragma unroll
      for (int p = 0; p < 4; ++p) {
        int row = p * 16 + (t >> 4);
        int ch = (t & 15) * 8;
        *(uint4*)(&T[(size_t)(nb + row) * D_MODEL + mbase + ch]) =
            *(const uint4*)(&sm.qk[row][ch]);
      }
    } else {
#pragma unroll
      for (int tm = 0; tm < 2; ++tm) {
        int m0 = w * 32 + tm * 16 + g * 4;
#pragma unroll
        for (int tn = 0; tn < 4; ++tn) {
          int nl = tn * 16 + l16;
#pragma unroll
          for (int r = 0; r < 4; ++r)
            ((f16*)&sm.v[m0 + r][0])[nl] = (f16)acc[tm][tn][r];
        }
      }
      __syncthreads();
      int mbase = mb - 2 * D_MODEL;
#pragma unroll
      for (int p = 0; p < 4; ++p) {
        int row = p * 32 + (t >> 3);
        int ch = (t & 7) * 8;
        *(uint4*)(&Vb[(size_t)(mbase + row) * SEQ_N + nb + ch]) =
            *(const uint4*)(&sm.v[row][ch]);
      }
    }
  }
  gridbar(ctr + 32);
  // ================= P3: attention (R7 body, JSPLIT=2, 1024 blocks) =================
  {
    int xcd = b & 7, slot = b >> 3;
    int combo = xcd * 4 + (slot >> 5);   // 0..31
    int qt = slot & 31;
    int h = combo & 15;
    int sp = combo >> 4;                 // 0..1
    int ib = qt * 64;
    int j0 = sp * JCHUNK;
    bf16x8 bq[2];
    {
      const u16* qb = Qt + (size_t)(ib + w * 16 + l16) * D_MODEL + h * DHEAD + g * 8;
      bq[0] = *(const bf16x8*)(qb);
      bq[1] = *(const bf16x8*)(qb + 32);
    }
    f32x4 acc_o[4];
#pragma unroll
    for (int i = 0; i < 4; ++i) acc_o[i] = (f32x4){0.f, 0.f, 0.f, 0.f};
    float lsum = 0.f;
    int srow = t >> 3, sch = (t & 7) * 8;
    for (int it = 0; it < JCHUNK / 64; ++it) {
      int jb = j0 + it * 64;
      uint4 kr0 = *(const uint4*)(&Kt[(size_t)(jb + srow) * D_MODEL + h * DHEAD + sch]);
      uint4 kr1 = *(const uint4*)(&Kt[(size_t)(jb + srow + 32) * D_MODEL + h * DHEAD + sch]);
      uint4 vr0 = *(const uint4*)(&Vb[(size_t)(h * DHEAD + srow) * SEQ_N + jb + sch]);
      uint4 vr1 = *(const uint4*)(&Vb[(size_t)(h * DHEAD + srow + 32) * SEQ_N + jb + sch]);
      *(uint4*)(&sm.at.K[srow][sch]) = kr0;
      *(uint4*)(&sm.at.K[srow + 32][sch]) = kr1;
      *(uint4*)(&sm.at.V[srow][sch]) = vr0;
      *(uint4*)(&sm.at.V[srow + 32][sch]) = vr1;
      __syncthreads();
      f32x4 s[4];
#pragma unroll
      for (int i = 0; i < 4; ++i) s[i] = (f32x4){0.f, 0.f, 0.f, 0.f};
#pragma unroll
      for (int kk = 0; kk < 2; ++kk)
#pragma unroll
        for (int tn = 0; tn < 4; ++tn) {
          bf16x8 ak = *(const bf16x8*)(&sm.at.K[tn * 16 + l16][kk * 32 + g * 8]);
          s[tn] = __builtin_amdgcn_mfma_f32_16x16x32_bf16(ak, bq[kk], s[tn], 0, 0, 0);
        }
      f16x4 pf[4];
#pragma unroll
      for (int tn = 0; tn < 4; ++tn)
#pragma unroll
        for (int r = 0; r < 4; ++r) {
          float pv = exp2f(fmaf(s[tn][r], 0.18033688f, -5.7707801f));
          lsum += pv;
          pf[tn][r] = (f16)pv;
        }
#pragma unroll
      for (int tn = 0; tn < 4; ++tn)
#pragma unroll
        for (int td = 0; td < 4; ++td) {
          f16x4 bv = *(const f16x4*)(&sm.at.V[td * 16 + l16][tn * 16 + g * 4]);
          acc_o[td] =
              __builtin_amdgcn_mfma_f32_16x16x16f16(pf[tn], bv, acc_o[td], 0, 0, 0);
        }
      __syncthreads();
    }
    lsum += __shfl_xor(lsum, 16, 64);
    lsum += __shfl_xor(lsum, 32, 64);
    if (g == 0)
      Lpart[((size_t)sp * HEADS + h) * SEQ_N + ib + w * 16 + l16] = lsum;
#pragma unroll
    for (int td = 0; td < 4; ++td) {
      int dhl = td * 16 + l16;
#pragma unroll
      for (int r = 0; r < 4; ++r)
        sm.at.V[w * 16 + g * 4 + r][dhl] = (f16)acc_o[td][r];
    }
    __syncthreads();
#pragma unroll
    for (int p = 0; p < 2; ++p) {
      int row = p * 32 + (t >> 3);
      int ch = (t & 7) * 8;
      *(uint4*)(&Opart[((size_t)sp * SEQ_N + ib + row) * D_MODEL + h * DHEAD + ch]) =
          *(const uint4*)(&sm.at.V[row][ch]);
    }
  }
  gridbar(ctr + 48);
  // ================= P4: combine (2 rows per block) =================
  {
#pragma unroll
    for (int rr = 0; rr < 2; ++rr) {
      int i = b * 2 + rr;
      int c = t * 4;
      int h = c >> 6;
      float l = 0.f;
#pragma unroll
      for (int s = 0; s < JSPLIT; ++s) l += Lpart[((size_t)s * HEADS + h) * SEQ_N + i];
      float o[4] = {0.f, 0.f, 0.f, 0.f};
#pragma unroll
      for (int s = 0; s < JSPLIT; ++s) {
        f16x4 v = *(const f16x4*)(&Opart[((size_t)s * SEQ_N + i) * D_MODEL + c]);
#pragma unroll
        for (int r = 0; r < 4; ++r) o[r] += (float)v[r];
      }
      float inv = 1.0f / l;
      ushort4 ob;
      ob.x = f2bf(o[0] * inv); ob.y = f2bf(o[1] * inv);
      ob.z = f2bf(o[2] * inv); ob.w = f2bf(o[3] * inv);
      *(ushort4*)(&attnt[(size_t)i * D_MODEL + c]) = ob;
    }
  }
  gridbar(ctr + 64);
  // ================= P5: out-proj GEMM 64x64 (512 blocks) =================
  if (b < 512) {
    int xcd = b & 7, s2 = b >> 3;
    int mt = xcd * 2 + (s2 & 1);
    int nt = s2 >> 1;
    int mb = mt * 64, nb = nt * 64;
    f32x4 acc[4];
#pragma unroll
    for (int i = 0; i < 4; ++i) acc[i] = (f32x4){0.f, 0.f, 0.f, 0.f};
    int srow = t >> 2, scol = (t & 3) * 8;
    const u16* Ag = W0p + (size_t)(mb + srow) * D_MODEL + scol;
    const u16* Bg = attnt + (size_t)(nb + srow) * D_MODEL + scol;
    for (int kb = 0; kb < D_MODEL; kb += 32) {
      ASYNC16(Ag + kb, &sm.g.A[t * 8]);
      ASYNC16(Bg + kb, &sm.g.B[t * 8]);
      __syncthreads();
      bf16x8 af = *(const bf16x8*)(&sm.g.A[(w * 16 + l16) * 32 + g * 8]);
#pragma unroll
      for (int tn = 0; tn < 4; ++tn) {
        bf16x8 bf = *(const bf16x8*)(&sm.g.B[(tn * 16 + l16) * 32 + g * 8]);
        acc[tn] = __builtin_amdgcn_mfma_f32_16x16x32_bf16(af, bf, acc[tn], 0, 0, 0);
      }
      __syncthreads();
    }
    int col0 = nb + l16;
    int row0 = mb + w * 16 + g * 4;
#pragma unroll
    for (int tn = 0; tn < 4; ++tn) {
      int col = col0 + tn * 16;
#pragma unroll
      for (int r = 0; r < 4; ++r) {
        int row = row0 + r;
        out[(size_t)row * SEQ_N + col] =
            acc[tn][r] + x[(size_t)row * SEQ_N + col];
      }
    }
  }
}

// ---------------- launch ----------------
extern "C" void kernel_launch(void* const* d_in, const int* in_sizes, int n_in,
                              void* d_out, int out_size, void* d_ws, size_t ws_size,
                              hipStream_t stream) {
  const float* x  = (const float*)d_in[0];
  const float* WQ = (const float*)d_in[1];
  const float* WK = (const float*)d_in[2];
  const float* WV = (const float*)d_in[3];
  const float* W0 = (const float*)d_in[4];
  float* out = (float*)d_out;

  char* ws = (char*)d_ws;
  size_t off = 0;
  unsigned* ctr  = (unsigned*)(ws + off); off += 4096;                     // 5 barrier counters (64B apart)
  double* part   = (double*)(ws + off); off += 16384;                      // 1024 x 2 doubles
  u16*    xnt    = (u16*)(ws + off); off += (size_t)SEQ_N * D_MODEL * 2;
  u16*    Wp     = (u16*)(ws + off); off += (size_t)M3 * D_MODEL * 2;
  u16*    W0p    = (u16*)(ws + off); off += (size_t)D_MODEL * D_MODEL * 2;
  u16*    Qt     = (u16*)(ws + off); off += (size_t)SEQ_N * D_MODEL * 2;
  u16*    Kt     = (u16*)(ws + off); off += (size_t)SEQ_N * D_MODEL * 2;
  f16*    Vb     = (f16*)(ws + off); off += (size_t)D_MODEL * SEQ_N * 2;
  u16*    attnt  = (u16*)(ws + off); off += (size_t)SEQ_N * D_MODEL * 2;
  f16*    Opart  = (f16*)(ws + off); off += (size_t)JSPLIT * SEQ_N * D_MODEL * 2;
  float*  Lpart  = (float*)(ws + off); off += (size_t)JSPLIT * HEADS * SEQ_N * 4;

  hipMemsetAsync(ctr, 0, 4096, stream);   // zero barrier counters (capturable node)
  mega<<<NBLK, 256, 0, stream>>>(x, WQ, WK, WV, W0, out, ctr, part, xnt, Wp, W0p,
                                 Qt, Kt, Vb, attnt, Opart, Lpart);
}